// Round 6
// baseline (170.928 us; speedup 1.0000x reference)
//
#include <hip/hip_runtime.h>

// MHA: B=8, H=8, S=1024, E=512, KEY_DIM=512, dh=64. fp32 I/O, bf16 MFMA, fp32 accum.
// 4 dispatches: prep -> gemm_qkv -> attn -> gemm_o.
// R6: BOTH GEMMs are LDS-free & barrier-free (R3 attn pattern): prep/attn emit
// all GEMM inputs in FRAGMENT-LINEAR layout (one MFMA fragment = one contiguous
// 1KB wave load), so waves stream A/B frags from L2 into registers (ping-pong)
// and run MFMA independently. attn unchanged except Oc written fragment-linear.
//
// Fragment-linear layout for a [R][512] bf16 matrix (K=512 -> 16 granules):
//   elem (r,k) at ((r>>4)*16 + (k>>5))*512 + (((k>>3)&3)*16 + (r&15))*8 + (k&7)
// A-frag (rt, kg) = rows rt*16..+15, k kg*32..+31; lane quad*16+l16 holds
// row l16, k quad*8..+7 -- identical to the verified LDS-staged read layout.

typedef __bf16 bf16x8 __attribute__((ext_vector_type(8)));
typedef __bf16 bf16x4 __attribute__((ext_vector_type(4)));
typedef float  f32x4  __attribute__((ext_vector_type(4)));

#define MFMA(a, b, c) __builtin_amdgcn_mfma_f32_16x16x32_bf16((a), (b), (c), 0, 0, 0)

__device__ inline float fast_exp2(float x) {
  float r;
  asm("v_exp_f32 %0, %1" : "=v"(r) : "v"(x));
  return r;
}

__device__ inline bf16x8 cvt8(const float* p) {
  f32x4 u = *(const f32x4*)p;
  f32x4 v = *(const f32x4*)(p + 4);
  bf16x8 r;
  r[0] = (__bf16)u[0]; r[1] = (__bf16)u[1]; r[2] = (__bf16)u[2]; r[3] = (__bf16)u[3];
  r[4] = (__bf16)v[0]; r[5] = (__bf16)v[1]; r[6] = (__bf16)v[2]; r[7] = (__bf16)v[3];
  return r;
}

// ---------------------------------------------------------------------------
// prep: blocks 0..2047: fp32->bf16 of Q,K,V into FRAGMENT-LINEAR layout.
//       blocks 2048..2303: transpose 4 fp32 512x512 weights -> bf16 W^T
//       fragment-linear; qscale (1/sqrt(512)*log2e) folded into Wq.
// ---------------------------------------------------------------------------
__global__ __launch_bounds__(256) void prep(
    const float* __restrict__ Q, const float* __restrict__ K,
    const float* __restrict__ V, __bf16* __restrict__ Qo,
    __bf16* __restrict__ Ko, __bf16* __restrict__ Vo,
    const float* __restrict__ W0, const float* __restrict__ W1,
    const float* __restrict__ W2, const float* __restrict__ W3,
    __bf16* __restrict__ O0, __bf16* __restrict__ O1,
    __bf16* __restrict__ O2, __bf16* __restrict__ O3, float s0) {
  const int bx = blockIdx.x;
  if (bx < 2048) {
    const long e0 = ((long)bx * 256 + threadIdx.x) * 8;  // 8-aligned elem index
    const int m = (int)(e0 >> 9), k = (int)(e0 & 511);
    const long fa = ((long)((m >> 4) * 16 + (k >> 5))) * 512 +
                    ((((k >> 3) & 3) * 16 + (m & 15)) << 3);
    *(bf16x8*)(Qo + fa) = cvt8(Q + e0);
    *(bf16x8*)(Ko + fa) = cvt8(K + e0);
    *(bf16x8*)(Vo + fa) = cvt8(V + e0);
    return;
  }
  const int bx2 = bx - 2048;
  const float* in;
  __bf16* out;
  float sc = 1.0f;
  switch (bx2 >> 6) {
    case 0: in = W0; out = O0; sc = s0; break;
    case 1: in = W1; out = O1; break;
    case 2: in = W2; out = O2; break;
    default: in = W3; out = O3; break;
  }
  const int ti = bx2 & 63;
  __shared__ __align__(16) float t[64][65];
  const int tk = (ti & 7) * 64;
  const int tn = (ti >> 3) * 64;
  const int r0 = threadIdx.x >> 4;
  const int c4 = threadIdx.x & 15;
#pragma unroll
  for (int i = 0; i < 4; ++i) {
    int r = r0 + i * 16;
    f32x4 v = *(const f32x4*)(in + (long)(tk + r) * 512 + tn + c4 * 4);
#pragma unroll
    for (int j = 0; j < 4; ++j) t[r][c4 * 4 + j] = v[j] * sc;
  }
  __syncthreads();
  const int n0 = threadIdx.x >> 3;
  const int k8 = threadIdx.x & 7;
#pragma unroll
  for (int i = 0; i < 2; ++i) {
    const int n = tn + n0 + i * 32;     // W^T row
    const int k = tk + k8 * 8;          // 8-aligned k
    bf16x8 v;
#pragma unroll
    for (int j = 0; j < 8; ++j) v[j] = (__bf16)t[k8 * 8 + j][n0 + i * 32];
    const long fa = ((long)((n >> 4) * 16 + (k >> 5))) * 512 +
                    ((((k >> 3) & 3) * 16 + (n & 15)) << 3);
    *(bf16x8*)(out + fa) = v;
  }
}

// ---------------------------------------------------------------------------
// Register-streaming GEMM core (LDS-free, barrier-free):
// C = X[8192,512] @ Wt[n][k] + bias*bsc, X/Wt fragment-linear bf16.
// Tile: (MT*32) x 128, 4 waves in 2x2 (wave = MT*16 x 64). K fully traversed
// in 16 steps of 32; A/B frags ping-pong in registers; per step MT+4 1KB
// wave-loads from L2 + 4*MT MFMA under setprio. XCD swizzle on bm.
// MODE 0: fp32 [m*512+n]
// MODE 1: bf16 split-head [((b*8+h)*1024+s)*64+d]
// MODE 3: bf16 K FRAGMENT-LINEAR chunk layout (attn)
// MODE 4: bf16 V^T FRAGMENT-LINEAR chunk layout (epilogue LDS bounce; MT=4)
// ---------------------------------------------------------------------------
template <int MODE, int MT, typename OT>
__device__ __forceinline__ void gemm_core(const __bf16* __restrict__ X,
                                          const __bf16* __restrict__ Wt,
                                          const float* __restrict__ bias,
                                          OT* __restrict__ out, float bsc,
                                          char* smem) {
  constexpr int TM = MT * 32;          // tile m-rows
  constexpr int MPX = 8192 / TM / 8;   // m-tiles per XCD slot
  const int tid = threadIdx.x;
  const int lane = tid & 63, wid = tid >> 6, quad = lane >> 4, l16 = lane & 15;
  const int i = blockIdx.x;
  const int kk = i >> 3;
  const int bm = ((i & 7) * MPX + (kk >> 2)) * TM;  // XCD-local m-range
  const int bn = (kk & 3) * 128;
  const int wm = (wid >> 1) * (MT * 16);
  const int wn = (wid & 1) * 64;

  const __bf16* Xf = X + (long)((bm + wm) >> 4) * 16 * 512 + lane * 8;
  const __bf16* Wf = Wt + (long)((bn + wn) >> 4) * 16 * 512 + lane * 8;

  f32x4 acc[MT][4] = {};

  auto loadab = [&](bf16x8 (&a)[MT], bf16x8 (&b)[4], int cc) {
#pragma unroll
    for (int t = 0; t < MT; ++t)
      a[t] = *(const bf16x8*)(Xf + (long)(t * 16 + cc) * 512);
#pragma unroll
    for (int t = 0; t < 4; ++t)
      b[t] = *(const bf16x8*)(Wf + (long)(t * 16 + cc) * 512);
  };
  auto mfmaall = [&](const bf16x8 (&a)[MT], const bf16x8 (&b)[4]) {
    __builtin_amdgcn_s_setprio(1);
#pragma unroll
    for (int mt = 0; mt < MT; ++mt)
#pragma unroll
      for (int nt = 0; nt < 4; ++nt) acc[mt][nt] = MFMA(a[mt], b[nt], acc[mt][nt]);
    __builtin_amdgcn_s_setprio(0);
  };

  bf16x8 aA[MT], bA[4], aB[MT], bB[4];
  loadab(aA, bA, 0);
#pragma unroll 1
  for (int c = 0; c < 16; c += 2) {
    loadab(aB, bB, c + 1);
    mfmaall(aA, bA);
    if (c < 14) loadab(aA, bA, c + 2);
    mfmaall(aB, bB);
  }

  if constexpr (MODE == 4) {
    // ---- epilogue transpose: C tile -> LDS (granule-swizzled) -> V frags ----
    __syncthreads();  // reuse smem as 128x128 bf16 tile (MT=4 only)
    __bf16* tb = (__bf16*)smem;
#pragma unroll
    for (int nt = 0; nt < 4; ++nt) {
      const int n = wn + nt * 16 + l16;  // tile-local n (= hh*64 + d)
      const float bvv = bias[bn + n] * bsc;
#pragma unroll
      for (int mt = 0; mt < 4; ++mt) {
        const int m0 = wm + mt * 16 + quad * 4;  // tile-local m
        bf16x4 w;
#pragma unroll
        for (int r = 0; r < 4; ++r) w[r] = (__bf16)(acc[mt][nt][r] + bvv);
        *(bf16x4*)(&tb[n * 128 + (((m0 >> 3) ^ (n & 15)) << 3) + (m0 & 7)]) = w;
      }
    }
    __syncthreads();
    const int nn = tid & 127, mhalf = tid >> 7;
    const int h = (bn + nn) >> 6;
    const int bb = bm >> 10;
    OT* ob = out + (long)(bb * 8 + h) * 65536;
    const int cbase = (bm & 1023) >> 6;  // chunk base within pair
#pragma unroll
    for (int gi = 0; gi < 8; ++gi) {
      const int gl = mhalf * 8 + gi;  // m-granule: srow = (bm&1023) + gl*8 + j
      bf16x8 v = *(const bf16x8*)(&tb[nn * 128 + ((gl ^ (nn & 15)) << 3)]);
      const long idx = ((((long)(cbase + (gl >> 3)) * 4 + ((nn >> 4) & 3)) * 2 +
                        ((gl >> 2) & 1)) * 64 + (gl & 3) * 16 + (nn & 15)) * 8;
      *(bf16x8*)(ob + idx) = v;
    }
    return;
  }

#pragma unroll
  for (int nt = 0; nt < 4; ++nt) {
    const int n = bn + wn + nt * 16 + l16;
    const float bvv = bias[n] * bsc;
    const int h = n >> 6, d = n & 63;
#pragma unroll
    for (int mt = 0; mt < MT; ++mt) {
#pragma unroll
      for (int r = 0; r < 4; ++r) {
        const int m = bm + wm + mt * 16 + quad * 4 + r;
        const float v = acc[mt][nt][r] + bvv;
        if constexpr (MODE == 0) {
          out[(long)m * 512 + n] = (OT)v;
        } else if constexpr (MODE == 1) {
          const int bb = m >> 10, s = m & 1023;
          out[((long)((bb * 8 + h) * 1024 + s)) * 64 + d] = (OT)v;
        } else {  // MODE 3: K fragment-linear chunks
          const int bb = m >> 10, s = m & 1023;
          const long idx = (long)(bb * 8 + h) * 65536 +
                           ((((s >> 6) * 4 + ((s >> 4) & 3)) * 2 + (d >> 5)) * 64 +
                            ((d >> 3) & 3) * 16 + (s & 15)) * 8 + (d & 7);
          out[idx] = (OT)v;
        }
      }
    }
  }
}

// Fused Q/K/V projections from fragment-linear bf16 copies: grid (256,3) x 256.
__global__ __launch_bounds__(256, 3) void gemm_qkv(
    const __bf16* __restrict__ Qx, const __bf16* __restrict__ Kx,
    const __bf16* __restrict__ Vx, const __bf16* __restrict__ Wqt,
    const __bf16* __restrict__ Wkt, const __bf16* __restrict__ Wvt,
    const float* __restrict__ bq, const float* __restrict__ bk,
    const float* __restrict__ bv, __bf16* __restrict__ Qp,
    __bf16* __restrict__ Kp, __bf16* __restrict__ Vtp, float qscale) {
  __shared__ __align__(16) char smem[32768];  // MODE 4 epilogue bounce only
  if (blockIdx.y == 0)
    gemm_core<1, 4, __bf16>(Qx, Wqt, bq, Qp, qscale, smem);
  else if (blockIdx.y == 1)
    gemm_core<3, 4, __bf16>(Kx, Wkt, bk, Kp, 1.0f, smem);
  else
    gemm_core<4, 4, __bf16>(Vx, Wvt, bv, Vtp, 1.0f, smem);
}

// Output projection: Oc(frag-linear) @ Wot + bo -> fp32. 64x128 tiles, 512 blk.
__global__ __launch_bounds__(256, 3) void gemm_o(const __bf16* __restrict__ Oc,
                                                 const __bf16* __restrict__ Wot,
                                                 const float* __restrict__ bo,
                                                 float* __restrict__ out) {
  gemm_core<0, 2, float>(Oc, Wot, bo, out, 1.0f, nullptr);
}

// ---------------------------------------------------------------------------
// Flash attention, BARRIER-FREE (verified R3 form): K/V fragments streamed from
// L2; K reg-double-buffered; P via wave-private LDS; no-max softmax (exact:
// |s| <= ~2.2*log2e); raw v_exp_f32. R6: Oc written FRAGMENT-LINEAR for gemm_o.
// ---------------------------------------------------------------------------
__global__ __launch_bounds__(256, 2) void attn(const __bf16* __restrict__ Q,
                                               const __bf16* __restrict__ Kf,
                                               const __bf16* __restrict__ Vf,
                                               __bf16* __restrict__ Oc) {
  __shared__ __align__(16) __bf16 plds[4][2048];

  const int tid = threadIdx.x;
  const int lane = tid & 63, wid = tid >> 6, quad = lane >> 4, l16 = lane & 15;
  const int i = blockIdx.x;
  const int pair = (i & 7) + (((i >> 6) & 7) << 3);  // XCD-local pair
  const int qt = (i >> 3) & 7;
  const int q0 = qt * 128 + wid * 32;
  const int b = pair >> 3, h = pair & 7;
  const int swz = l16 & 7;

  const __bf16* Qb = Q + (long)pair * 65536;
  const __bf16* Kb = Kf + (long)pair * 65536 + lane * 8;  // frag base + lane slot
  const __bf16* Vb = Vf + (long)pair * 65536 + lane * 8;
  __bf16* pw = plds[wid];

  bf16x8 bq[2][2];
#pragma unroll
  for (int t = 0; t < 2; ++t)
#pragma unroll
    for (int e = 0; e < 2; ++e)
      bq[t][e] = *(const bf16x8*)(Qb + (q0 + t * 16 + l16) * 64 + e * 32 + quad * 8);

  f32x4 lrv[2] = {};
  f32x4 oa[2][4] = {};

#define LOADK(dst, cc)                                                         \
  {                                                                            \
    _Pragma("unroll") for (int kt = 0; kt < 4; ++kt)                           \
        _Pragma("unroll") for (int e = 0; e < 2; ++e)                          \
            dst[kt][e] =                                                       \
        *(const bf16x8*)(Kb + ((((cc) * 4 + kt) * 2 + e) << 9));               \
  }

#define ABODY(kcur, knxt, cc)                                                  \
  {                                                                            \
    bf16x8 vf[4][2];                                                           \
    _Pragma("unroll") for (int nt = 0; nt < 4; ++nt)                           \
        _Pragma("unroll") for (int e = 0; e < 2; ++e)                          \
            vf[nt][e] =                                                        \
        *(const bf16x8*)(Vb + ((((cc) * 4 + nt) * 2 + e) << 9));               \
    f32x4 s[2][4] = {};                                                        \
    __builtin_amdgcn_s_setprio(1);                                             \
    _Pragma("unroll") for (int kt = 0; kt < 4; ++kt)                           \
        _Pragma("unroll") for (int t = 0; t < 2; ++t) {                        \
      s[t][kt] = MFMA(kcur[kt][0], bq[t][0], s[t][kt]);                        \
      s[t][kt] = MFMA(kcur[kt][1], bq[t][1], s[t][kt]);                        \
    }                                                                          \
    __builtin_amdgcn_s_setprio(0);                                             \
    if ((cc) < 15) LOADK(knxt, (cc) + 1);                                      \
    _Pragma("unroll") for (int t = 0; t < 2; ++t) {                            \
      const int prow = (t * 16 + l16) * 64;                                    \
      _Pragma("unroll") for (int kt = 0; kt < 4; ++kt) {                       \
        bf16x4 w;                                                              \
        _Pragma("unroll") for (int r = 0; r < 4; ++r) {                        \
          const float p = fast_exp2(s[t][kt][r]);                              \
          lrv[t][r] += p;                                                      \
          w[r] = (__bf16)p;                                                    \
        }                                                                      \
        *(bf16x4*)(&pw[prow + (((kt * 2 + (quad >> 1)) ^ swz) << 3) +          \
                       (quad & 1) * 4]) = w;                                   \
      }                                                                        \
    }                                                                          \
    bf16x8 pb[2][2];                                                           \
    _Pragma("unroll") for (int t = 0; t < 2; ++t)                              \
        _Pragma("unroll") for (int e = 0; e < 2; ++e)                          \
            pb[t][e] = *(const bf16x8*)(&pw[(t * 16 + l16) * 64 +              \
                                            (((e * 4 + quad) ^ swz) << 3)]);   \
    __builtin_amdgcn_s_setprio(1);                                             \
    _Pragma("unroll") for (int nt = 0; nt < 4; ++nt)                           \
        _Pragma("unroll") for (int t = 0; t < 2; ++t) {                        \
      oa[t][nt] = MFMA(vf[nt][0], pb[t][0], oa[t][nt]);                        \
      oa[t][nt] = MFMA(vf[nt][1], pb[t][1], oa[t][nt]);                        \
    }                                                                          \
    __builtin_amdgcn_s_setprio(0);                                             \
  }

  bf16x8 kA[4][2], kB[4][2];
  LOADK(kA, 0);
#pragma unroll 1
  for (int c = 0; c < 16; c += 2) {
    ABODY(kA, kB, c);
    ABODY(kB, kA, c + 1);
  }
#undef LOADK
#undef ABODY

#pragma unroll
  for (int t = 0; t < 2; ++t) {
    float lr = lrv[t][0] + lrv[t][1] + lrv[t][2] + lrv[t][3];
    lr += __shfl_xor(lr, 16);
    lr += __shfl_xor(lr, 32);
    const float inv = 1.0f / lr;
    const int mrow = b * 1024 + q0 + t * 16;  // + l16 per-lane (m&15 = l16)
#pragma unroll
    for (int nt = 0; nt < 4; ++nt) {
      bf16x4 w;
#pragma unroll
      for (int r = 0; r < 4; ++r) w[r] = (__bf16)(oa[t][nt][r] * inv);
      const int n = h * 64 + nt * 16 + quad * 4;  // + r (n&7 = (quad&1)*4 + r)
      const long fa = ((long)((mrow >> 4) * 16 + (n >> 5))) * 512 +
                      ((((n >> 3) & 3) * 16 + l16) << 3) + (n & 7);
      *(bf16x4*)(Oc + fa) = w;
    }
  }
}

// ---------------------------------------------------------------------------
extern "C" void kernel_launch(void* const* d_in, const int* in_sizes, int n_in,
                              void* d_out, int out_size, void* d_ws, size_t ws_size,
                              hipStream_t stream) {
  const float* queries = (const float*)d_in[0];
  const float* keys = (const float*)d_in[1];
  const float* values = (const float*)d_in[2];
  const float* Wq = (const float*)d_in[3];
  const float* bq = (const float*)d_in[4];
  const float* Wk = (const float*)d_in[5];
  const float* bk = (const float*)d_in[6];
  const float* Wv = (const float*)d_in[7];
  const float* bv = (const float*)d_in[8];
  const float* Wo = (const float*)d_in[9];
  const float* bo = (const float*)d_in[10];
  float* out = (float*)d_out;

  __bf16* ws = (__bf16*)d_ws;
  const long WSZ = 512 * 512;
  const long XSZ = 8192L * 512;
  __bf16* Wqt = ws;                // W^T frag-linear, Wq pre-scaled log2e/sqrt(512)
  __bf16* Wkt = ws + WSZ;
  __bf16* Wvt = ws + 2 * WSZ;
  __bf16* Wot = ws + 3 * WSZ;
  __bf16* Qp = ws + 4 * WSZ;       // [pair][s][64], pre-scaled
  __bf16* Kp = Qp + XSZ;           // K fragment-linear chunks (attn)
  __bf16* Vtp = Kp + XSZ;          // V^T fragment-linear chunks (attn)
  __bf16* Oc = Vtp + XSZ;          // attn out, fragment-linear (gemm_o input)
  __bf16* Qbf = Oc + XSZ;          // bf16 frag-linear copies of fp32 inputs
  __bf16* Kbf = Qbf + XSZ;
  __bf16* Vbf = Kbf + XSZ;

  // 1/sqrt(512) * log2(e): softmax uses exp2 (bare v_exp_f32)
  const float qscale = 0.044194173824159216f * 1.4426950408889634f;

  prep<<<2304, 256, 0, stream>>>(queries, keys, values, Qbf, Kbf, Vbf,
                                 Wq, Wk, Wv, Wo, Wqt, Wkt, Wvt, Wot, qscale);

  gemm_qkv<<<dim3(256, 3), 256, 0, stream>>>(Qbf, Kbf, Vbf, Wqt, Wkt, Wvt,
                                             bq, bk, bv, Qp, Kp, Vtp, qscale);

  attn<<<512, 256, 0, stream>>>(Qp, Kp, Vtp, Oc);

  gemm_o<<<512, 256, 0, stream>>>(Oc, Wot, bo, out);
}

// Round 7
// 163.789 us; speedup vs baseline: 1.0436x; 1.0436x over previous
//
#include <hip/hip_runtime.h>

// MHA: B=8, H=8, S=1024, E=512, KEY_DIM=512, dh=64. fp32 I/O, bf16 MFMA, fp32 accum.
// 4 dispatches: prep -> gemm_qkv -> attn -> gemm_o.
// R7: GEMMs back to verified R5 LDS machinery (gl_lds triple-buffer, counted
// vmcnt + raw barrier, granule swizzle) but with BIG tiles: 256m x 128n per
// block, wave-tile 128x64 (32 MFMA per K-step per wave) to amortize the
// 2-phase stage/wait/barrier stall. LDS 72KB -> 2 blocks/CU. attn/prep = R5.

typedef __bf16 bf16x8 __attribute__((ext_vector_type(8)));
typedef __bf16 bf16x4 __attribute__((ext_vector_type(4)));
typedef float  f32x4  __attribute__((ext_vector_type(4)));

#define MFMA(a, b, c) __builtin_amdgcn_mfma_f32_16x16x32_bf16((a), (b), (c), 0, 0, 0)

// counted-wait + barrier in ONE volatile asm (staging pipelines)
#define WAITN_BAR(N) asm volatile("s_waitcnt vmcnt(" #N ")\n\ts_barrier" ::: "memory")

__device__ inline float fast_exp2(float x) {
  float r;
  asm("v_exp_f32 %0, %1" : "=v"(r) : "v"(x));
  return r;
}

__device__ inline bf16x8 cvt8(const float* p) {
  f32x4 u = *(const f32x4*)p;
  f32x4 v = *(const f32x4*)(p + 4);
  bf16x8 r;
  r[0] = (__bf16)u[0]; r[1] = (__bf16)u[1]; r[2] = (__bf16)u[2]; r[3] = (__bf16)u[3];
  r[4] = (__bf16)v[0]; r[5] = (__bf16)v[1]; r[6] = (__bf16)v[2]; r[7] = (__bf16)v[3];
  return r;
}

// async global->LDS, 16 B per lane (dest = wave-uniform base + lane*16)
__device__ inline void gl_lds(const __bf16* g, __bf16* l) {
  __builtin_amdgcn_global_load_lds((const __attribute__((address_space(1))) void*)g,
                                   (__attribute__((address_space(3))) void*)l, 16, 0, 0);
}

// ---------------------------------------------------------------------------
// prep (verified R5): blocks 0..2047: fp32->bf16 of Q,K,V (linear layout);
// blocks 2048..2303: transpose 4 fp32 512x512 weights -> bf16 [n][k];
// qscale (1/sqrt(512)*log2e) folded into Wq.
// ---------------------------------------------------------------------------
__global__ __launch_bounds__(256) void prep(
    const float* __restrict__ Q, const float* __restrict__ K,
    const float* __restrict__ V, __bf16* __restrict__ Qo,
    __bf16* __restrict__ Ko, __bf16* __restrict__ Vo,
    const float* __restrict__ W0, const float* __restrict__ W1,
    const float* __restrict__ W2, const float* __restrict__ W3,
    __bf16* __restrict__ O0, __bf16* __restrict__ O1,
    __bf16* __restrict__ O2, __bf16* __restrict__ O3, float s0) {
  const int bx = blockIdx.x;
  if (bx < 2048) {
    const long idx = ((long)bx * 256 + threadIdx.x) * 8;
    *(bf16x8*)(Qo + idx) = cvt8(Q + idx);
    *(bf16x8*)(Ko + idx) = cvt8(K + idx);
    *(bf16x8*)(Vo + idx) = cvt8(V + idx);
    return;
  }
  const int bx2 = bx - 2048;
  const float* in;
  __bf16* out;
  float sc = 1.0f;
  switch (bx2 >> 6) {
    case 0: in = W0; out = O0; sc = s0; break;
    case 1: in = W1; out = O1; break;
    case 2: in = W2; out = O2; break;
    default: in = W3; out = O3; break;
  }
  const int ti = bx2 & 63;
  __shared__ __align__(16) float t[64][65];
  const int tk = (ti & 7) * 64;
  const int tn = (ti >> 3) * 64;
  const int r0 = threadIdx.x >> 4;
  const int c4 = threadIdx.x & 15;
#pragma unroll
  for (int i = 0; i < 4; ++i) {
    int r = r0 + i * 16;
    f32x4 v = *(const f32x4*)(in + (long)(tk + r) * 512 + tn + c4 * 4);
#pragma unroll
    for (int j = 0; j < 4; ++j) t[r][c4 * 4 + j] = v[j] * sc;
  }
  __syncthreads();
  const int n0 = threadIdx.x >> 3;
  const int k8 = threadIdx.x & 7;
#pragma unroll
  for (int i = 0; i < 2; ++i) {
    int n = n0 + i * 32;
    bf16x8 v;
#pragma unroll
    for (int j = 0; j < 8; ++j) v[j] = (__bf16)t[k8 * 8 + j][n];
    *(bf16x8*)(out + (long)(tn + n) * 512 + tk + k8 * 8) = v;
  }
}

// ---------------------------------------------------------------------------
// Staged GEMM core (R7 big-tile): C = X[8192,512](bf16) @ Wt[n][k] + bias*bsc.
// Block tile 256m x 128n, 4 waves (wave = 128m x 64n, acc 8x4, 32 MFMA/step).
// BK=32, 16 K-steps, TRIPLE-buffered LDS: A 3x8192 elem (48KB), B 3x4096
// (24KB). Per wave per step 6 gl_lds -> depth-2 counted vmcnt(6) + raw barrier.
// Granule swizzle (verified): store granule g of row r at g ^ ((r>>1)&3);
// read with posm = quad ^ ((l16>>1)&3). XCD swizzle on bm.
// MODE 0: fp32 [m*512+n]
// MODE 1: bf16 split-head [((b*8+h)*1024+s)*64+d]
// MODE 3: bf16 K FRAGMENT-LINEAR chunk layout (attn)
// MODE 4: bf16 V^T chunk layout via TWO per-wave-pair 128^2 LDS bounces
// ---------------------------------------------------------------------------
template <int MODE, typename OT>
__device__ __forceinline__ void gemm_core(const __bf16* __restrict__ X,
                                          const __bf16* __restrict__ Wt,
                                          const float* __restrict__ bias,
                                          OT* __restrict__ out, float bsc,
                                          char* smem) {
  __bf16* At = (__bf16*)smem;            // 3 buffers x 8192 elements (48 KB)
  __bf16* Bt = (__bf16*)(smem + 49152);  // 3 buffers x 4096 elements (24 KB)

  const int tid = threadIdx.x;
  const int lane = tid & 63, wid = tid >> 6, quad = lane >> 4, l16 = lane & 15;
  const int i = blockIdx.x;
  const int kk = i >> 3;                           // 0..15
  const int bm = ((i & 7) * 4 + (kk >> 2)) * 256;  // XCD-local m-range
  const int bn = (kk & 3) * 128;
  const int wm = (wid >> 1) * 128;
  const int wn = (wid & 1) * 64;

  f32x4 acc[8][4] = {};

  const int rowB = lane >> 2;                     // 0..15 row within 16-row group
  const int gB = (lane & 3) ^ ((rowB >> 1) & 3);  // conflict-free gather granule

  // 6 gl_lds per wave per stage (4 A-groups + 2 B-groups of 16 rows)
  auto stage = [&](int oa, int ob, int k0) {
#pragma unroll
    for (int j = 0; j < 4; ++j) {
      const int g = wid * 4 + j;  // A rows g*16..g*16+15 (0..255)
      gl_lds(X + (long)(bm + g * 16 + rowB) * 512 + k0 + (gB << 3),
             &At[oa + g * 512 + lane * 8]);
    }
#pragma unroll
    for (int j = 0; j < 2; ++j) {
      const int g = wid * 2 + j;  // B rows g*16..g*16+15 (0..127)
      gl_lds(Wt + (long)(bn + g * 16 + rowB) * 512 + k0 + (gB << 3),
             &Bt[ob + g * 512 + lane * 8]);
    }
  };

  const int posm = quad ^ ((l16 >> 1) & 3);  // matches (row>>1)&3 store swizzle

  auto compute = [&](int oa, int ob) {
    bf16x8 a[8], b[4];
#pragma unroll
    for (int t = 0; t < 8; ++t)
      a[t] = *(const bf16x8*)(&At[oa + (wm + t * 16 + l16) * 32 + (posm << 3)]);
#pragma unroll
    for (int t = 0; t < 4; ++t)
      b[t] = *(const bf16x8*)(&Bt[ob + (wn + t * 16 + l16) * 32 + (posm << 3)]);
#pragma unroll
    for (int mt = 0; mt < 8; ++mt)
#pragma unroll
      for (int nt = 0; nt < 4; ++nt) acc[mt][nt] = MFMA(a[mt], b[nt], acc[mt][nt]);
  };

  stage(0, 0, 0);
  stage(8192, 4096, 32);

  // rotate: co* = compute buffer offset, so* = buffer to stage into
  int coA = 0, soA = 16384, coB = 0, soB = 8192;
  for (int c = 0; c < 15; ++c) {
    WAITN_BAR(6);                // tile c landed (tile c+1's 6 stay in flight)
    if (c < 14) stage(soA, soB, (c + 2) * 32);
    compute(coA, coB);
    const int nA = 24576 - coA - soA;
    soA = coA; coA = nA;
    const int nB = 12288 - coB - soB;
    soB = coB; coB = nB;
  }
  WAITN_BAR(0);
  compute(coA, coB);

  if constexpr (MODE == 4) {
    // ---- epilogue transpose: two independent 128^2 half-bounces ------------
    __syncthreads();  // all frag reads done; reuse smem
    const int half = wid >> 1;                       // wave-pair id (rows wm)
    __bf16* tb = (__bf16*)smem + half * 16384;       // 32 KB region each
#pragma unroll
    for (int nt = 0; nt < 4; ++nt) {
      const int n = wn + nt * 16 + l16;  // tile-local n (= hh*64 + d), 0..127
      const float bvv = bias[bn + n] * bsc;
#pragma unroll
      for (int mt = 0; mt < 8; ++mt) {
        const int m0 = mt * 16 + quad * 4;  // local m within half, 0..127
        bf16x4 w;
#pragma unroll
        for (int r = 0; r < 4; ++r) w[r] = (__bf16)(acc[mt][nt][r] + bvv);
        *(bf16x4*)(&tb[n * 128 + (((m0 >> 3) ^ (n & 15)) << 3) + (m0 & 7)]) = w;
      }
    }
    __syncthreads();
    // threads 0..127 drain half 0 (their own waves' region), 128..255 half 1
    const int nn = tid & 127;
    const int h = (bn + nn) >> 6;
    const int bb = bm >> 10;
    OT* ob2 = out + (long)(bb * 8 + h) * 65536;
    const int mbase = (bm & 1023) + half * 128;
    const int cbase = mbase >> 6;
#pragma unroll
    for (int gl = 0; gl < 16; ++gl) {  // m-granule: srow = mbase + gl*8 + j
      bf16x8 v = *(const bf16x8*)(&tb[nn * 128 + ((gl ^ (nn & 15)) << 3)]);
      const long idx = ((((long)(cbase + (gl >> 3)) * 4 + ((nn >> 4) & 3)) * 2 +
                        ((gl >> 2) & 1)) * 64 + (gl & 3) * 16 + (nn & 15)) * 8;
      *(bf16x8*)(ob2 + idx) = v;
    }
    return;
  }

#pragma unroll
  for (int nt = 0; nt < 4; ++nt) {
    const int n = bn + wn + nt * 16 + l16;
    const float bvv = bias[n] * bsc;
    const int h = n >> 6, d = n & 63;
#pragma unroll
    for (int mt = 0; mt < 8; ++mt) {
#pragma unroll
      for (int r = 0; r < 4; ++r) {
        const int m = bm + wm + mt * 16 + quad * 4 + r;
        const float v = acc[mt][nt][r] + bvv;
        if constexpr (MODE == 0) {
          out[(long)m * 512 + n] = (OT)v;
        } else if constexpr (MODE == 1) {
          const int bb = m >> 10, s = m & 1023;
          out[((long)((bb * 8 + h) * 1024 + s)) * 64 + d] = (OT)v;
        } else {  // MODE 3: K fragment-linear chunks
          const int bb = m >> 10, s = m & 1023;
          const long idx = (long)(bb * 8 + h) * 65536 +
                           ((((s >> 6) * 4 + ((s >> 4) & 3)) * 2 + (d >> 5)) * 64 +
                            ((d >> 3) & 3) * 16 + (s & 15)) * 8 + (d & 7);
          out[idx] = (OT)v;
        }
      }
    }
  }
}

// Fused Q/K/V projections from bf16 copies: grid (128, 3) x 256 thr, 72KB dyn.
__global__ __launch_bounds__(256, 2) void gemm_qkv(
    const __bf16* __restrict__ Qx, const __bf16* __restrict__ Kx,
    const __bf16* __restrict__ Vx, const __bf16* __restrict__ Wqt,
    const __bf16* __restrict__ Wkt, const __bf16* __restrict__ Wvt,
    const float* __restrict__ bq, const float* __restrict__ bk,
    const float* __restrict__ bv, __bf16* __restrict__ Qp,
    __bf16* __restrict__ Kp, __bf16* __restrict__ Vtp, float qscale) {
  extern __shared__ __align__(16) char smem[];
  if (blockIdx.y == 0)
    gemm_core<1, __bf16>(Qx, Wqt, bq, Qp, qscale, smem);
  else if (blockIdx.y == 1)
    gemm_core<3, __bf16>(Kx, Wkt, bk, Kp, 1.0f, smem);
  else
    gemm_core<4, __bf16>(Vx, Wvt, bv, Vtp, 1.0f, smem);
}

// Output projection: Oc[8192,512] bf16 @ Wot + bo -> fp32 out. Grid 128.
__global__ __launch_bounds__(256, 2) void gemm_o(const __bf16* __restrict__ Oc,
                                                 const __bf16* __restrict__ Wot,
                                                 const float* __restrict__ bo,
                                                 float* __restrict__ out) {
  extern __shared__ __align__(16) char smem[];
  gemm_core<0, float>(Oc, Wot, bo, out, 1.0f, smem);
}

// ---------------------------------------------------------------------------
// Flash attention, BARRIER-FREE (verified R3/R5 form): K/V fragments streamed
// from L2 (fragment-linear chunk layouts, one 1KB coalesced wave load each);
// K reg-double-buffered; P via wave-private LDS; transposed no-max softmax
// (exact: |s| <= ~2.2*log2e); raw v_exp_f32. Oc written [B,S,512].
// ---------------------------------------------------------------------------
__global__ __launch_bounds__(256, 2) void attn(const __bf16* __restrict__ Q,
                                               const __bf16* __restrict__ Kf,
                                               const __bf16* __restrict__ Vf,
                                               __bf16* __restrict__ Oc) {
  __shared__ __align__(16) __bf16 plds[4][2048];

  const int tid = threadIdx.x;
  const int lane = tid & 63, wid = tid >> 6, quad = lane >> 4, l16 = lane & 15;
  const int i = blockIdx.x;
  const int pair = (i & 7) + (((i >> 6) & 7) << 3);  // XCD-local pair
  const int qt = (i >> 3) & 7;
  const int q0 = qt * 128 + wid * 32;
  const int b = pair >> 3, h = pair & 7;
  const int swz = l16 & 7;

  const __bf16* Qb = Q + (long)pair * 65536;
  const __bf16* Kb = Kf + (long)pair * 65536 + lane * 8;  // frag base + lane slot
  const __bf16* Vb = Vf + (long)pair * 65536 + lane * 8;
  __bf16* pw = plds[wid];

  bf16x8 bq[2][2];
#pragma unroll
  for (int t = 0; t < 2; ++t)
#pragma unroll
    for (int e = 0; e < 2; ++e)
      bq[t][e] = *(const bf16x8*)(Qb + (q0 + t * 16 + l16) * 64 + e * 32 + quad * 8);

  f32x4 lrv[2] = {};
  f32x4 oa[2][4] = {};

#define LOADK(dst, cc)                                                         \
  {                                                                            \
    _Pragma("unroll") for (int kt = 0; kt < 4; ++kt)                           \
        _Pragma("unroll") for (int e = 0; e < 2; ++e)                          \
            dst[kt][e] =                                                       \
        *(const bf16x8*)(Kb + ((((cc) * 4 + kt) * 2 + e) << 9));               \
  }

#define ABODY(kcur, knxt, cc)                                                  \
  {                                                                            \
    bf16x8 vf[4][2];                                                           \
    _Pragma("unroll") for (int nt = 0; nt < 4; ++nt)                           \
        _Pragma("unroll") for (int e = 0; e < 2; ++e)                          \
            vf[nt][e] =                                                        \
        *(const bf16x8*)(Vb + ((((cc) * 4 + nt) * 2 + e) << 9));               \
    f32x4 s[2][4] = {};                                                        \
    __builtin_amdgcn_s_setprio(1);                                             \
    _Pragma("unroll") for (int kt = 0; kt < 4; ++kt)                           \
        _Pragma("unroll") for (int t = 0; t < 2; ++t) {                        \
      s[t][kt] = MFMA(kcur[kt][0], bq[t][0], s[t][kt]);                        \
      s[t][kt] = MFMA(kcur[kt][1], bq[t][1], s[t][kt]);                        \
    }                                                                          \
    __builtin_amdgcn_s_setprio(0);                                             \
    if ((cc) < 15) LOADK(knxt, (cc) + 1);                                      \
    _Pragma("unroll") for (int t = 0; t < 2; ++t) {                            \
      const int prow = (t * 16 + l16) * 64;                                    \
      _Pragma("unroll") for (int kt = 0; kt < 4; ++kt) {                       \
        bf16x4 w;                                                              \
        _Pragma("unroll") for (int r = 0; r < 4; ++r) {                        \
          const float p = fast_exp2(s[t][kt][r]);                              \
          lrv[t][r] += p;                                                      \
          w[r] = (__bf16)p;                                                    \
        }                                                                      \
        *(bf16x4*)(&pw[prow + (((kt * 2 + (quad >> 1)) ^ swz) << 3) +          \
                       (quad & 1) * 4]) = w;                                   \
      }                                                                        \
    }                                                                          \
    bf16x8 pb[2][2];                                                           \
    _Pragma("unroll") for (int t = 0; t < 2; ++t)                              \
        _Pragma("unroll") for (int e = 0; e < 2; ++e)                          \
            pb[t][e] = *(const bf16x8*)(&pw[(t * 16 + l16) * 64 +              \
                                            (((e * 4 + quad) ^ swz) << 3)]);   \
    __builtin_amdgcn_s_setprio(1);                                             \
    _Pragma("unroll") for (int nt = 0; nt < 4; ++nt)                           \
        _Pragma("unroll") for (int t = 0; t < 2; ++t) {                        \
      oa[t][nt] = MFMA(vf[nt][0], pb[t][0], oa[t][nt]);                        \
      oa[t][nt] = MFMA(vf[nt][1], pb[t][1], oa[t][nt]);                        \
    }                                                                          \
    __builtin_amdgcn_s_setprio(0);                                             \
  }

  bf16x8 kA[4][2], kB[4][2];
  LOADK(kA, 0);
#pragma unroll 1
  for (int c = 0; c < 16; c += 2) {
    ABODY(kA, kB, c);
    ABODY(kB, kA, c + 1);
  }
#undef LOADK
#undef ABODY

#pragma unroll
  for (int t = 0; t < 2; ++t) {
    float lr = lrv[t][0] + lrv[t][1] + lrv[t][2] + lrv[t][3];
    lr += __shfl_xor(lr, 16);
    lr += __shfl_xor(lr, 32);
    const float inv = 1.0f / lr;
    const long base = ((long)b * 1024 + q0 + t * 16 + l16) * 512 + h * 64 + quad * 4;
#pragma unroll
    for (int nt = 0; nt < 4; ++nt) {
      bf16x4 w;
#pragma unroll
      for (int r = 0; r < 4; ++r) w[r] = (__bf16)(oa[t][nt][r] * inv);
      *(bf16x4*)(Oc + base + nt * 16) = w;
    }
  }
}

// ---------------------------------------------------------------------------
extern "C" void kernel_launch(void* const* d_in, const int* in_sizes, int n_in,
                              void* d_out, int out_size, void* d_ws, size_t ws_size,
                              hipStream_t stream) {
  const float* queries = (const float*)d_in[0];
  const float* keys = (const float*)d_in[1];
  const float* values = (const float*)d_in[2];
  const float* Wq = (const float*)d_in[3];
  const float* bq = (const float*)d_in[4];
  const float* Wk = (const float*)d_in[5];
  const float* bk = (const float*)d_in[6];
  const float* Wv = (const float*)d_in[7];
  const float* bv = (const float*)d_in[8];
  const float* Wo = (const float*)d_in[9];
  const float* bo = (const float*)d_in[10];
  float* out = (float*)d_out;

  __bf16* ws = (__bf16*)d_ws;
  const long WSZ = 512 * 512;
  const long XSZ = 8192L * 512;
  __bf16* Wqt = ws;                // [512,512]^T bf16, Wq pre-scaled log2e/sqrt(512)
  __bf16* Wkt = ws + WSZ;
  __bf16* Wvt = ws + 2 * WSZ;
  __bf16* Wot = ws + 3 * WSZ;
  __bf16* Qp = ws + 4 * WSZ;       // [pair][s][64], pre-scaled
  __bf16* Kp = Qp + XSZ;           // K fragment-linear chunks (attn)
  __bf16* Vtp = Kp + XSZ;          // V^T fragment-linear chunks (attn)
  __bf16* Oc = Vtp + XSZ;          // [B,S,512]
  __bf16* Qbf = Oc + XSZ;          // bf16 copies of fp32 inputs
  __bf16* Kbf = Qbf + XSZ;
  __bf16* Vbf = Kbf + XSZ;

  // 1/sqrt(512) * log2(e): softmax uses exp2 (bare v_exp_f32)
  const float qscale = 0.044194173824159216f * 1.4426950408889634f;

  prep<<<2304, 256, 0, stream>>>(queries, keys, values, Qbf, Kbf, Vbf,
                                 Wq, Wk, Wv, Wo, Wqt, Wkt, Wvt, Wot, qscale);

  gemm_qkv<<<dim3(128, 3), 256, 73728, stream>>>(Qbf, Kbf, Vbf, Wqt, Wkt, Wvt,
                                                 bq, bk, bv, Qp, Kp, Vtp, qscale);

  attn<<<512, 256, 0, stream>>>(Qp, Kp, Vtp, Oc);

  gemm_o<<<128, 256, 73728, stream>>>(Oc, Wot, bo, out);
}

// Round 8
// 159.398 us; speedup vs baseline: 1.0723x; 1.0275x over previous
//
#include <hip/hip_runtime.h>

// MHA: B=8, H=8, S=1024, E=512, KEY_DIM=512, dh=64. fp32 I/O, bf16 MFMA, fp32 accum.
// 4 dispatches: prep -> gemm_qkv -> attn -> gemm_o. R8 = R5 (best, 161.5us) +
// vectorized MODE 1/3 epilogues: acc -> LDS bounce (m-major, granule-XOR m&15,
// conflict-free) -> bf16x8 stores (8 VMEM/thread instead of 64 scalar 2B).

typedef __bf16 bf16x8 __attribute__((ext_vector_type(8)));
typedef __bf16 bf16x4 __attribute__((ext_vector_type(4)));
typedef float  f32x4  __attribute__((ext_vector_type(4)));

#define MFMA(a, b, c) __builtin_amdgcn_mfma_f32_16x16x32_bf16((a), (b), (c), 0, 0, 0)

// counted-wait + barrier in ONE volatile asm (staging pipelines)
#define WAITN_BAR(N) asm volatile("s_waitcnt vmcnt(" #N ")\n\ts_barrier" ::: "memory")

__device__ inline float fast_exp2(float x) {
  float r;
  asm("v_exp_f32 %0, %1" : "=v"(r) : "v"(x));
  return r;
}

__device__ inline bf16x8 cvt8(const float* p) {
  f32x4 u = *(const f32x4*)p;
  f32x4 v = *(const f32x4*)(p + 4);
  bf16x8 r;
  r[0] = (__bf16)u[0]; r[1] = (__bf16)u[1]; r[2] = (__bf16)u[2]; r[3] = (__bf16)u[3];
  r[4] = (__bf16)v[0]; r[5] = (__bf16)v[1]; r[6] = (__bf16)v[2]; r[7] = (__bf16)v[3];
  return r;
}

// async global->LDS, 16 B per lane (dest = wave-uniform base + lane*16)
__device__ inline void gl_lds(const __bf16* g, __bf16* l) {
  __builtin_amdgcn_global_load_lds((const __attribute__((address_space(1))) void*)g,
                                   (__attribute__((address_space(3))) void*)l, 16, 0, 0);
}

// ---------------------------------------------------------------------------
// prep (verified R5): blocks 0..2047: fp32->bf16 of Q,K,V (linear layout);
// blocks 2048..2303: transpose 4 fp32 512x512 weights -> bf16 [n][k];
// qscale (1/sqrt(512)*log2e) folded into Wq.
// ---------------------------------------------------------------------------
__global__ __launch_bounds__(256) void prep(
    const float* __restrict__ Q, const float* __restrict__ K,
    const float* __restrict__ V, __bf16* __restrict__ Qo,
    __bf16* __restrict__ Ko, __bf16* __restrict__ Vo,
    const float* __restrict__ W0, const float* __restrict__ W1,
    const float* __restrict__ W2, const float* __restrict__ W3,
    __bf16* __restrict__ O0, __bf16* __restrict__ O1,
    __bf16* __restrict__ O2, __bf16* __restrict__ O3, float s0) {
  const int bx = blockIdx.x;
  if (bx < 2048) {
    const long idx = ((long)bx * 256 + threadIdx.x) * 8;
    *(bf16x8*)(Qo + idx) = cvt8(Q + idx);
    *(bf16x8*)(Ko + idx) = cvt8(K + idx);
    *(bf16x8*)(Vo + idx) = cvt8(V + idx);
    return;
  }
  const int bx2 = bx - 2048;
  const float* in;
  __bf16* out;
  float sc = 1.0f;
  switch (bx2 >> 6) {
    case 0: in = W0; out = O0; sc = s0; break;
    case 1: in = W1; out = O1; break;
    case 2: in = W2; out = O2; break;
    default: in = W3; out = O3; break;
  }
  const int ti = bx2 & 63;
  __shared__ __align__(16) float t[64][65];
  const int tk = (ti & 7) * 64;
  const int tn = (ti >> 3) * 64;
  const int r0 = threadIdx.x >> 4;
  const int c4 = threadIdx.x & 15;
#pragma unroll
  for (int i = 0; i < 4; ++i) {
    int r = r0 + i * 16;
    f32x4 v = *(const f32x4*)(in + (long)(tk + r) * 512 + tn + c4 * 4);
#pragma unroll
    for (int j = 0; j < 4; ++j) t[r][c4 * 4 + j] = v[j] * sc;
  }
  __syncthreads();
  const int n0 = threadIdx.x >> 3;
  const int k8 = threadIdx.x & 7;
#pragma unroll
  for (int i = 0; i < 2; ++i) {
    int n = n0 + i * 32;
    bf16x8 v;
#pragma unroll
    for (int j = 0; j < 8; ++j) v[j] = (__bf16)t[k8 * 8 + j][n];
    *(bf16x8*)(out + (long)(tn + n) * 512 + tk + k8 * 8) = v;
  }
}

// ---------------------------------------------------------------------------
// Staged GEMM core (verified R5): C = X[8192,512](bf16) @ Wt[n][k] + bias*bsc.
// 128x128 tile, 4 waves (64x64), BK=32. Triple-buffered LDS (48 KB) via
// global_load_lds(16B), counted vmcnt(4) + raw barrier. Granule swizzle:
// store granule g of row r at g ^ ((r>>1)&3); read posm = quad ^ ((l16>>1)&3).
// XCD swizzle on bm.
// MODE 0: fp32 [m*512+n] (scalar f32 stores)
// MODE 1: bf16 split-head [((b*8+h)*1024+s)*64+d]  (R8: LDS-bounce epilogue)
// MODE 3: bf16 K FRAGMENT-LINEAR chunk layout      (R8: LDS-bounce epilogue)
// MODE 4: bf16 V^T chunk layout (verified LDS bounce)
// ---------------------------------------------------------------------------
template <int MODE, typename OT>
__device__ __forceinline__ void gemm_core(const __bf16* __restrict__ X,
                                          const __bf16* __restrict__ Wt,
                                          const float* __restrict__ bias,
                                          OT* __restrict__ out, float bsc,
                                          char* smem) {
  __bf16* At = (__bf16*)smem;            // 3 buffers x 4096 elements (24 KB)
  __bf16* Bt = (__bf16*)(smem + 24576);  // 3 buffers x 4096 elements (24 KB)

  const int tid = threadIdx.x;
  const int lane = tid & 63, wid = tid >> 6, quad = lane >> 4, l16 = lane & 15;
  const int i = blockIdx.x;
  const int kk = i >> 3;
  const int bm = ((i & 7) * 8 + (kk >> 2)) * 128;  // XCD-local m-range
  const int bn = (kk & 3) * 128;
  const int wm = (wid >> 1) * 64;
  const int wn = (wid & 1) * 64;

  f32x4 acc[4][4] = {};

  const int rowB = lane >> 2;                     // 0..15 row within 16-row group
  const int gB = (lane & 3) ^ ((rowB >> 1) & 3);  // conflict-free gather granule

  // 4 gl_lds per wave per stage
  auto stage = [&](int off, int k0) {
#pragma unroll
    for (int j = 0; j < 2; ++j) {
      const int g = wid * 2 + j;  // rows g*16..g*16+15
      gl_lds(X + (long)(bm + g * 16 + rowB) * 512 + k0 + (gB << 3),
             &At[off + g * 512 + lane * 8]);
      gl_lds(Wt + (long)(bn + g * 16 + rowB) * 512 + k0 + (gB << 3),
             &Bt[off + g * 512 + lane * 8]);
    }
  };

  const int posm = quad ^ ((l16 >> 1) & 3);  // matches (row>>1)&3 store swizzle

  auto compute = [&](int co) {
    bf16x8 a[4], b[4];
#pragma unroll
    for (int t = 0; t < 4; ++t) {
      a[t] = *(const bf16x8*)(&At[co + (wm + t * 16 + l16) * 32 + (posm << 3)]);
      b[t] = *(const bf16x8*)(&Bt[co + (wn + t * 16 + l16) * 32 + (posm << 3)]);
    }
#pragma unroll
    for (int mt = 0; mt < 4; ++mt)
#pragma unroll
      for (int nt = 0; nt < 4; ++nt) acc[mt][nt] = MFMA(a[mt], b[nt], acc[mt][nt]);
  };

  stage(0, 0);
  stage(4096, 32);

  int co = 0, so = 8192;  // compute offset, stage offset (elements)
  for (int c = 0; c < 15; ++c) {
    WAITN_BAR(4);                         // tile c landed (c+1 stays in flight)
    if (c < 14) stage(so, (c + 2) * 32);  // overwrites buffer read in iter c-1
    compute(co);
    const int nc = 12288 - co - so;
    so = co;
    co = nc;
  }
  WAITN_BAR(0);  // last tile: nothing left in flight to preserve
  compute(co);

  if constexpr (MODE == 1 || MODE == 3) {
    // ---- R8 epilogue: acc -> m-major LDS tile (granule-XOR m&15) -> bf16x8 --
    // Write: one scalar ds_write per (nt,mt,r); lanes = (quad -> 4 distinct
    // granule-quads via XOR, l16 -> 16 consecutive bf16 = 2 lanes/bank) ->
    // conflict-free. Drain: 8 consecutive m rows hit 8 distinct granules.
    __syncthreads();  // all frag reads done; smem reused as 128x128 bf16 tile
    __bf16* tb = (__bf16*)smem;
#pragma unroll
    for (int nt = 0; nt < 4; ++nt) {
      const int n = wn + nt * 16 + l16;
      const float bvv = bias[bn + n] * bsc;
#pragma unroll
      for (int mt = 0; mt < 4; ++mt) {
#pragma unroll
        for (int r = 0; r < 4; ++r) {
          const int m = wm + mt * 16 + quad * 4 + r;
          tb[m * 128 + ((((n >> 3) ^ (m & 15)) << 3) | (n & 7))] =
              (__bf16)(acc[mt][nt][r] + bvv);
        }
      }
    }
    __syncthreads();
#pragma unroll
    for (int p = 0; p < 4; ++p) {
#pragma unroll
      for (int hf = 0; hf < 2; ++hf) {
        const int m = p * 32 + (tid >> 3);        // tile-local s-row
        const int g = (tid & 7) + hf * 8;         // n-granule (8 elems)
        bf16x8 v = *(const bf16x8*)(&tb[m * 128 + ((g ^ (m & 15)) << 3)]);
        const int sg = bm + m;
        const int bb = sg >> 10, s = sg & 1023;
        const int n0 = bn + g * 8;
        const int h = n0 >> 6, d0 = n0 & 63;
        if constexpr (MODE == 1) {
          *(bf16x8*)(out + ((long)((bb * 8 + h) * 1024 + s)) * 64 + d0) = v;
        } else {  // MODE 3: K fragment-linear chunks (d0 8-aligned -> d&7 run)
          const long idx = (long)(bb * 8 + h) * 65536 +
                           ((((s >> 6) * 4 + ((s >> 4) & 3)) * 2 + (d0 >> 5)) * 64 +
                            ((d0 >> 3) & 3) * 16 + (s & 15)) * 8;
          *(bf16x8*)(out + idx) = v;
        }
      }
    }
    return;
  }

  if constexpr (MODE == 4) {
    // ---- epilogue transpose: C tile -> LDS (granule-swizzled) -> V frags ----
    __syncthreads();  // all frag reads done; smem reused as 128x128 bf16 tile
    __bf16* tb = (__bf16*)smem;
#pragma unroll
    for (int nt = 0; nt < 4; ++nt) {
      const int n = wn + nt * 16 + l16;  // tile-local n (= hh*64 + d)
      const float bvv = bias[bn + n] * bsc;
#pragma unroll
      for (int mt = 0; mt < 4; ++mt) {
        const int m0 = wm + mt * 16 + quad * 4;  // tile-local m
        bf16x4 w;
#pragma unroll
        for (int r = 0; r < 4; ++r) w[r] = (__bf16)(acc[mt][nt][r] + bvv);
        *(bf16x4*)(&tb[n * 128 + (((m0 >> 3) ^ (n & 15)) << 3) + (m0 & 7)]) = w;
      }
    }
    __syncthreads();
    const int nn = tid & 127, mhalf = tid >> 7;
    const int h = (bn + nn) >> 6;
    const int bb = bm >> 10;
    OT* ob = out + (long)(bb * 8 + h) * 65536;
    const int cbase = (bm & 1023) >> 6;  // chunk base within pair
#pragma unroll
    for (int gi = 0; gi < 8; ++gi) {
      const int gl = mhalf * 8 + gi;  // m-granule: srow = (bm&1023) + gl*8 + j
      bf16x8 v = *(const bf16x8*)(&tb[nn * 128 + ((gl ^ (nn & 15)) << 3)]);
      const long idx = ((((long)(cbase + (gl >> 3)) * 4 + ((nn >> 4) & 3)) * 2 +
                        ((gl >> 2) & 1)) * 64 + (gl & 3) * 16 + (nn & 15)) * 8;
      *(bf16x8*)(ob + idx) = v;
    }
    return;
  }

  // MODE 0: fp32 [m*512+n]
#pragma unroll
  for (int nt = 0; nt < 4; ++nt) {
    const int n = bn + wn + nt * 16 + l16;
    const float bvv = bias[n] * bsc;
#pragma unroll
    for (int mt = 0; mt < 4; ++mt) {
#pragma unroll
      for (int r = 0; r < 4; ++r) {
        const int m = bm + wm + mt * 16 + quad * 4 + r;
        out[(long)m * 512 + n] = (OT)(acc[mt][nt][r] + bvv);
      }
    }
  }
}

// Fused Q/K/V projections from bf16 copies: grid (256, 3) x 256 thr.
__global__ __launch_bounds__(256) void gemm_qkv(
    const __bf16* __restrict__ Qx, const __bf16* __restrict__ Kx,
    const __bf16* __restrict__ Vx, const __bf16* __restrict__ Wqt,
    const __bf16* __restrict__ Wkt, const __bf16* __restrict__ Wvt,
    const float* __restrict__ bq, const float* __restrict__ bk,
    const float* __restrict__ bv, __bf16* __restrict__ Qp,
    __bf16* __restrict__ Kp, __bf16* __restrict__ Vtp, float qscale) {
  __shared__ __align__(16) char smem[49152];
  if (blockIdx.y == 0)
    gemm_core<1, __bf16>(Qx, Wqt, bq, Qp, qscale, smem);
  else if (blockIdx.y == 1)
    gemm_core<3, __bf16>(Kx, Wkt, bk, Kp, 1.0f, smem);
  else
    gemm_core<4, __bf16>(Vx, Wvt, bv, Vtp, 1.0f, smem);
}

// Output projection: Oc[8192,512] bf16 @ Wot + bo -> fp32 out.
__global__ __launch_bounds__(256) void gemm_o(const __bf16* __restrict__ Oc,
                                              const __bf16* __restrict__ Wot,
                                              const float* __restrict__ bo,
                                              float* __restrict__ out) {
  __shared__ __align__(16) char smem[49152];
  gemm_core<0, float>(Oc, Wot, bo, out, 1.0f, smem);
}

// ---------------------------------------------------------------------------
// Flash attention, BARRIER-FREE (verified R3/R5 form): K/V fragments streamed
// from L2 (fragment-linear chunk layouts, one 1KB coalesced wave load each);
// K reg-double-buffered; P via wave-private LDS; transposed no-max softmax
// (exact: |s| <= ~2.2*log2e); raw v_exp_f32. Oc written [B,S,512].
// ---------------------------------------------------------------------------
__global__ __launch_bounds__(256, 2) void attn(const __bf16* __restrict__ Q,
                                               const __bf16* __restrict__ Kf,
                                               const __bf16* __restrict__ Vf,
                                               __bf16* __restrict__ Oc) {
  __shared__ __align__(16) __bf16 plds[4][2048];

  const int tid = threadIdx.x;
  const int lane = tid & 63, wid = tid >> 6, quad = lane >> 4, l16 = lane & 15;
  const int i = blockIdx.x;
  const int pair = (i & 7) + (((i >> 6) & 7) << 3);  // XCD-local pair
  const int qt = (i >> 3) & 7;
  const int q0 = qt * 128 + wid * 32;
  const int b = pair >> 3, h = pair & 7;
  const int swz = l16 & 7;

  const __bf16* Qb = Q + (long)pair * 65536;
  const __bf16* Kb = Kf + (long)pair * 65536 + lane * 8;  // frag base + lane slot
  const __bf16* Vb = Vf + (long)pair * 65536 + lane * 8;
  __bf16* pw = plds[wid];

  bf16x8 bq[2][2];
#pragma unroll
  for (int t = 0; t < 2; ++t)
#pragma unroll
    for (int e = 0; e < 2; ++e)
      bq[t][e] = *(const bf16x8*)(Qb + (q0 + t * 16 + l16) * 64 + e * 32 + quad * 8);

  f32x4 lrv[2] = {};
  f32x4 oa[2][4] = {};

#define LOADK(dst, cc)                                                         \
  {                                                                            \
    _Pragma("unroll") for (int kt = 0; kt < 4; ++kt)                           \
        _Pragma("unroll") for (int e = 0; e < 2; ++e)                          \
            dst[kt][e] =                                                       \
        *(const bf16x8*)(Kb + ((((cc) * 4 + kt) * 2 + e) << 9));               \
  }

#define ABODY(kcur, knxt, cc)                                                  \
  {                                                                            \
    bf16x8 vf[4][2];                                                           \
    _Pragma("unroll") for (int nt = 0; nt < 4; ++nt)                           \
        _Pragma("unroll") for (int e = 0; e < 2; ++e)                          \
            vf[nt][e] =                                                        \
        *(const bf16x8*)(Vb + ((((cc) * 4 + nt) * 2 + e) << 9));               \
    f32x4 s[2][4] = {};                                                        \
    __builtin_amdgcn_s_setprio(1);                                             \
    _Pragma("unroll") for (int kt = 0; kt < 4; ++kt)                           \
        _Pragma("unroll") for (int t = 0; t < 2; ++t) {                        \
      s[t][kt] = MFMA(kcur[kt][0], bq[t][0], s[t][kt]);                        \
      s[t][kt] = MFMA(kcur[kt][1], bq[t][1], s[t][kt]);                        \
    }                                                                          \
    __builtin_amdgcn_s_setprio(0);                                             \
    if ((cc) < 15) LOADK(knxt, (cc) + 1);                                      \
    _Pragma("unroll") for (int t = 0; t < 2; ++t) {                            \
      const int prow = (t * 16 + l16) * 64;                                    \
      _Pragma("unroll") for (int kt = 0; kt < 4; ++kt) {                       \
        bf16x4 w;                                                              \
        _Pragma("unroll") for (int r = 0; r < 4; ++r) {                        \
          const float p = fast_exp2(s[t][kt][r]);                              \
          lrv[t][r] += p;                                                      \
          w[r] = (__bf16)p;                                                    \
        }                                                                      \
        *(bf16x4*)(&pw[prow + (((kt * 2 + (quad >> 1)) ^ swz) << 3) +          \
                       (quad & 1) * 4]) = w;                                   \
      }                                                                        \
    }                                                                          \
    bf16x8 pb[2][2];                                                           \
    _Pragma("unroll") for (int t = 0; t < 2; ++t)                              \
        _Pragma("unroll") for (int e = 0; e < 2; ++e)                          \
            pb[t][e] = *(const bf16x8*)(&pw[(t * 16 + l16) * 64 +              \
                                            (((e * 4 + quad) ^ swz) << 3)]);   \
    __builtin_amdgcn_s_setprio(1);                                             \
    _Pragma("unroll") for (int nt = 0; nt < 4; ++nt)                           \
        _Pragma("unroll") for (int t = 0; t < 2; ++t) {                        \
      oa[t][nt] = MFMA(vf[nt][0], pb[t][0], oa[t][nt]);                        \
      oa[t][nt] = MFMA(vf[nt][1], pb[t][1], oa[t][nt]);                        \
    }                                                                          \
    __builtin_amdgcn_s_setprio(0);                                             \
  }

  bf16x8 kA[4][2], kB[4][2];
  LOADK(kA, 0);
#pragma unroll 1
  for (int c = 0; c < 16; c += 2) {
    ABODY(kA, kB, c);
    ABODY(kB, kA, c + 1);
  }
#undef LOADK
#undef ABODY

#pragma unroll
  for (int t = 0; t < 2; ++t) {
    float lr = lrv[t][0] + lrv[t][1] + lrv[t][2] + lrv[t][3];
    lr += __shfl_xor(lr, 16);
    lr += __shfl_xor(lr, 32);
    const float inv = 1.0f / lr;
    const long base = ((long)b * 1024 + q0 + t * 16 + l16) * 512 + h * 64 + quad * 4;
#pragma unroll
    for (int nt = 0; nt < 4; ++nt) {
      bf16x4 w;
#pragma unroll
      for (int r = 0; r < 4; ++r) w[r] = (__bf16)(oa[t][nt][r] * inv);
      *(bf16x4*)(Oc + base + nt * 16) = w;
    }
  }
}

// ---------------------------------------------------------------------------
extern "C" void kernel_launch(void* const* d_in, const int* in_sizes, int n_in,
                              void* d_out, int out_size, void* d_ws, size_t ws_size,
                              hipStream_t stream) {
  const float* queries = (const float*)d_in[0];
  const float* keys = (const float*)d_in[1];
  const float* values = (const float*)d_in[2];
  const float* Wq = (const float*)d_in[3];
  const float* bq = (const float*)d_in[4];
  const float* Wk = (const float*)d_in[5];
  const float* bk = (const float*)d_in[6];
  const float* Wv = (const float*)d_in[7];
  const float* bv = (const float*)d_in[8];
  const float* Wo = (const float*)d_in[9];
  const float* bo = (const float*)d_in[10];
  float* out = (float*)d_out;

  __bf16* ws = (__bf16*)d_ws;
  const long WSZ = 512 * 512;
  const long XSZ = 8192L * 512;
  __bf16* Wqt = ws;                // [512,512]^T bf16, Wq pre-scaled log2e/sqrt(512)
  __bf16* Wkt = ws + WSZ;
  __bf16* Wvt = ws + 2 * WSZ;
  __bf16* Wot = ws + 3 * WSZ;
  __bf16* Qp = ws + 4 * WSZ;       // [pair][s][64], pre-scaled
  __bf16* Kp = Qp + XSZ;           // K fragment-linear chunks (attn)
  __bf16* Vtp = Kp + XSZ;          // V^T fragment-linear chunks (attn)
  __bf16* Oc = Vtp + XSZ;          // [B,S,512]
  __bf16* Qbf = Oc + XSZ;          // bf16 copies of fp32 inputs
  __bf16* Kbf = Qbf + XSZ;
  __bf16* Vbf = Kbf + XSZ;

  // 1/sqrt(512) * log2(e): softmax uses exp2 (bare v_exp_f32)
  const float qscale = 0.044194173824159216f * 1.4426950408889634f;

  prep<<<2304, 256, 0, stream>>>(queries, keys, values, Qbf, Kbf, Vbf,
                                 Wq, Wk, Wv, Wo, Wqt, Wkt, Wvt, Wot, qscale);

  gemm_qkv<<<dim3(256, 3), 256, 0, stream>>>(Qbf, Kbf, Vbf, Wqt, Wkt, Wvt,
                                             bq, bk, bv, Qp, Kp, Vtp, qscale);

  attn<<<512, 256, 0, stream>>>(Qp, Kp, Vtp, Oc);

  gemm_o<<<256, 256, 0, stream>>>(Oc, Wot, bo, out);
}